// Round 19
// baseline (715.471 us; speedup 1.0000x reference)
//
#include <hip/hip_runtime.h>

// ---------------------------------------------------------------------------
// GAT fraud detector, round 11 (2nd resubmit — rounds 17/18 hit GPUAcquisitionTimeout):
//  sliced agg v4 — one THREAD per (node,chunk).
//  r10 post-mortem: byte cut held (FETCH 82MB) but wave count 4x'd (100K);
//  ~300 fixed instrs/wave (combines, cond loads, addressing) = measured 43us
//  VALU issue. v4 removes the wave tax: no cross-lane combine, no LDS, no
//  barriers, no wgt kernels (weight recomputed per thread: exp ~8 ops <<
//  combine machinery; kills 77MB pw traffic + 3 launches).
//  agg4: 256t = 64 nodes x 4 chunks, slice c=bid&7 -> XCD-resident 3.2MB
//  hbT slice; depth-2 pipeline (next srcs->sv->gather issued early).
//  agg1: 256t = 256 nodes x 1 thread (slice row = 16B).
//  GEMM epilogue writes hbT[slice][node][ch] (verified r9/r10); rest as r7b.
// ---------------------------------------------------------------------------

typedef unsigned int uint;
typedef unsigned short ushort;

#define NEG_SLOPE 0.2f
#define BN_EPS 1e-5f
#define NB_RED 256   // blocks for BN-stats / pool partial reductions

typedef __attribute__((ext_vector_type(2))) float f32x2;

__device__ __forceinline__ float bf2f(uint u) { return __uint_as_float(u << 16); }
__device__ __forceinline__ ushort f2bf(float f) {
    uint u = __float_as_uint(f);
    u += 0x7fff + ((u >> 16) & 1);   // round-nearest-even
    return (ushort)(u >> 16);
}

// ---------------- fused prep: cvt x -> bf16 (padded), transpose weights, histogram ----------------

__global__ void prep_kernel(const float* __restrict__ x, ushort* __restrict__ xb,
                            int total_real, int total_pad,
                            const float* __restrict__ W0, ushort* __restrict__ w0t,
                            const float* __restrict__ W1, ushort* __restrict__ w1t,
                            const float* __restrict__ W2, ushort* __restrict__ w2t,
                            const int* __restrict__ ei, int* __restrict__ deg, int E) {
    int i = blockIdx.x * blockDim.x + threadIdx.x;
    if (i < total_pad) {
        xb[i] = (i < total_real) ? f2bf(x[i]) : (ushort)0;
        return;
    }
    int j = i - total_pad;
    if (j < 32768) {                        // W0: K=128,F=256
        int n = j / 128, k = j - n * 128;
        w0t[j] = f2bf(W0[(size_t)k * 256 + n]);
        return;
    }
    j -= 32768;
    if (j < 65536) {                        // W1: K=256,F=256
        int n = j / 256, k = j - n * 256;
        w1t[j] = f2bf(W1[(size_t)k * 256 + n]);
        return;
    }
    j -= 65536;
    if (j < 16384) {                        // W2: K=256,F=64
        int n = j / 256, k = j - n * 256;
        w2t[j] = f2bf(W2[(size_t)k * 64 + n]);
        return;
    }
    j -= 16384;
    if (j < E) atomicAdd(&deg[ei[E + j]], 1);
}

// ---------------- CSR scan + scatter ----------------

__global__ void scan_part(const int* __restrict__ deg, int* __restrict__ offsets,
                          int* __restrict__ bsum, int N) {
    __shared__ int sh[256];
    int t = threadIdx.x;
    int base = blockIdx.x * 1024 + t * 4;
    int v0 = (base + 0 < N) ? deg[base + 0] : 0;
    int v1 = (base + 1 < N) ? deg[base + 1] : 0;
    int v2 = (base + 2 < N) ? deg[base + 2] : 0;
    int v3 = (base + 3 < N) ? deg[base + 3] : 0;
    int s = v0 + v1 + v2 + v3;
    sh[t] = s;
    __syncthreads();
    for (int off = 1; off < 256; off <<= 1) {
        int y = (t >= off) ? sh[t - off] : 0;
        __syncthreads();
        sh[t] += y;
        __syncthreads();
    }
    int p = sh[t] - s;
    if (base + 0 < N) offsets[base + 0] = p;
    p += v0;
    if (base + 1 < N) offsets[base + 1] = p;
    p += v1;
    if (base + 2 < N) offsets[base + 2] = p;
    p += v2;
    if (base + 3 < N) offsets[base + 3] = p;
    if (t == 255) bsum[blockIdx.x] = sh[255];
}

__global__ void scan_top(const int* __restrict__ bsum, int* __restrict__ bexcl,
                         int nb, int* __restrict__ offsets, int N) {
    if (threadIdx.x == 0) {
        int run = 0;
        for (int b = 0; b < nb; ++b) { bexcl[b] = run; run += bsum[b]; }
        offsets[N] = run;
    }
}

__global__ void scan_add(int* __restrict__ offsets, int* __restrict__ cursor,
                         const int* __restrict__ bexcl, int N) {
    int add = bexcl[blockIdx.x];
    int base = blockIdx.x * 1024 + threadIdx.x * 4;
#pragma unroll
    for (int k = 0; k < 4; ++k) {
        int i = base + k;
        if (i < N) { int v = offsets[i] + add; offsets[i] = v; cursor[i] = v; }
    }
}

__global__ void scatter_kernel(const int* __restrict__ ei, int* __restrict__ cursor,
                               int* __restrict__ srcs, int E) {
    int e = blockIdx.x * blockDim.x + threadIdx.x;
    if (e < E) {
        int s = ei[e];
        int d = ei[E + e];
        int p = atomicAdd(&cursor[d], 1);
        srcs[p] = s;
    }
}

// ---------------- bf16 MFMA GEMM, C stored CHANNEL-SLICED, fused sd epilogue ----------------
// C layout: [slice][Mpad][SCH] where SCH = 32 ch (BN=128 layers) or 8 ch (BN=64).

typedef __attribute__((ext_vector_type(8))) short bf16x8;
typedef __attribute__((ext_vector_type(4))) float floatx4;

template <int BN, int H>
__launch_bounds__(256)
__global__ void mfma_gemm_bt(const ushort* __restrict__ A, const ushort* __restrict__ Bt,
                             ushort* __restrict__ C, const float* __restrict__ asrc,
                             const float* __restrict__ adst, float* __restrict__ sv,
                             float* __restrict__ dv, int K, int Nn, int Mpad) {
    constexpr int WCOLS = (BN == 128) ? 2 : 1;
    constexpr int WROWS = 4 / WCOLS;
    constexpr int MT = 128 / (WROWS * 16);
    constexpr int NT = BN / (WCOLS * 16);
    constexpr int BCALLS = (BN * 32 * 2) / 4096;
    constexpr int SCH = (BN == 64) ? 8 : 32;     // slice width (channels)
    constexpr int SSH = (BN == 64) ? 3 : 5;      // log2(SCH)

    __shared__ ushort As[128 * 32];
    __shared__ ushort Bs[BN * 32];

    int t = threadIdx.x;
    int w = t >> 6, l = t & 63;

    int rb, cb;
    if (BN == 128) {
        int nbr = (int)gridDim.x >> 1;       // row tiles
        int full = (nbr & ~7) << 1;
        int id = blockIdx.x;
        if (id < full) {
            rb = ((id >> 4) << 3) + (id & 7);
            cb = (id >> 3) & 1;
        } else {
            int o = id - full;
            int rem = nbr & 7;
            rb = (nbr & ~7) + (rem ? (o % rem) : 0);
            cb = rem ? (o / rem) : 0;
        }
    } else {
        rb = blockIdx.x;
        cb = 0;
    }
    int row0 = rb * 128;
    int col0 = cb * BN;
    int wr = (w / WCOLS) * (MT * 16);
    int wc = (w % WCOLS) * (NT * 16);

    floatx4 acc[MT][NT];
#pragma unroll
    for (int mi = 0; mi < MT; ++mi)
#pragma unroll
        for (int ni = 0; ni < NT; ++ni)
#pragma unroll
            for (int r = 0; r < 4; ++r) acc[mi][ni][r] = 0.f;

    int mrow = l & 15;
    int kc = (l >> 4) * 8;

    for (int kt = 0; kt < K; kt += 32) {
#pragma unroll
        for (int c = 0; c < 2; ++c) {
            int idx = c * 256 + t;
            const ushort* gp = A + (size_t)(row0 + (idx >> 2)) * K + kt + (idx & 3) * 8;
            __builtin_amdgcn_global_load_lds(
                (const __attribute__((address_space(1))) void*)gp,
                (__attribute__((address_space(3))) void*)(As + (idx & ~63) * 8),
                16, 0, 0);
        }
#pragma unroll
        for (int c = 0; c < BCALLS; ++c) {
            int idx = c * 256 + t;
            const ushort* gp = Bt + (size_t)(col0 + (idx >> 2)) * K + kt + (idx & 3) * 8;
            __builtin_amdgcn_global_load_lds(
                (const __attribute__((address_space(1))) void*)gp,
                (__attribute__((address_space(3))) void*)(Bs + (idx & ~63) * 8),
                16, 0, 0);
        }
        __syncthreads();

        bf16x8 af[MT], bfr[NT];
#pragma unroll
        for (int mi = 0; mi < MT; ++mi)
            af[mi] = *(const bf16x8*)&As[(wr + mi * 16 + mrow) * 32 + kc];
#pragma unroll
        for (int ni = 0; ni < NT; ++ni)
            bfr[ni] = *(const bf16x8*)&Bs[(wc + ni * 16 + mrow) * 32 + kc];
#pragma unroll
        for (int mi = 0; mi < MT; ++mi)
#pragma unroll
            for (int ni = 0; ni < NT; ++ni)
                acc[mi][ni] = __builtin_amdgcn_mfma_f32_16x16x32_bf16(
                    af[mi], bfr[ni], acc[mi][ni], 0, 0, 0);
        __syncthreads();
    }

    // C store, channel-sliced: dst = ((col>>SSH)*Mpad + row)*SCH + (col&(SCH-1))
#pragma unroll
    for (int mi = 0; mi < MT; ++mi) {
        int rbase = row0 + wr + mi * 16 + (l >> 4) * 4;
#pragma unroll
        for (int ni = 0; ni < NT; ++ni) {
            int col = col0 + wc + ni * 16 + (l & 15);
            size_t sb = ((size_t)(col >> SSH) * Mpad) * SCH + (col & (SCH - 1));
#pragma unroll
            for (int r = 0; r < 4; ++r)
                C[sb + (size_t)(rbase + r) * SCH] = f2bf(acc[mi][ni][r]);
        }
    }

    // fused sd: this wave's NT*16 cols lie in exactly one head (64 cols).
    float av[NT], bv[NT];
#pragma unroll
    for (int ni = 0; ni < NT; ++ni) {
        int ch = col0 + wc + ni * 16 + (l & 15);
        av[ni] = asrc[ch];
        bv[ni] = adst[ch];
    }
    int gh = (col0 + wc) >> 6;
#pragma unroll
    for (int mi = 0; mi < MT; ++mi) {
#pragma unroll
        for (int r = 0; r < 4; ++r) {
            float s = 0.f, d = 0.f;
#pragma unroll
            for (int ni = 0; ni < NT; ++ni) {
                float hv = acc[mi][ni][r];
                s += hv * av[ni];
                d += hv * bv[ni];
            }
#pragma unroll
            for (int m = 8; m >= 1; m >>= 1) {
                s += __shfl_xor(s, m);
                d += __shfl_xor(d, m);
            }
            if ((l & 15) == 0) {
                int row = row0 + wr + mi * 16 + (l >> 4) * 4 + r;
                sv[row * H + gh] = s;
                dv[row * H + gh] = d;
            }
        }
    }
}

// ---------------- channel-sliced aggregation v4: one thread per (node,chunk) ----------------
// No LDS, no barriers, no cross-lane reduce. Weight recomputed per thread.
// Depth-2 software pipeline: next edge's srcs->sv->gather issued before the
// current edge is consumed.
// NOTE: macro params must NOT be named x/y/z/w (uint4 member capture).

#define ACCUMW4(qv_, wt_) { \
    f32x2 wv_ = {(wt_), (wt_)}; \
    uint pr_[4] = {(qv_).x, (qv_).y, (qv_).z, (qv_).w}; \
    _Pragma("unroll") \
    for (int k_ = 0; k_ < 4; ++k_) { \
        f32x2 hv_ = {__uint_as_float(pr_[k_] << 16), \
                     __uint_as_float(pr_[k_] & 0xffff0000u)}; \
        ax[k_] += wv_ * hv_; \
    } }

// agg4 (H=4, 256ch): slice c = bid&7 (32ch); 256t = 64 nodes x 4 chunks.
__launch_bounds__(256)
__global__ void agg4_kernel(const ushort* __restrict__ hbT, const float* __restrict__ sv,
                            const float* __restrict__ dv, const int* __restrict__ offsets,
                            const int* __restrict__ srcs, const float* __restrict__ bias,
                            ushort* __restrict__ zb, int N, int Mpad) {
    int t = threadIdx.x;
    int nlocal = t >> 2, chunk = t & 3;
    int bid = blockIdx.x;
    int c = bid & 7;                    // slice = XCD (round-robin mapping)
    int head = c >> 1;
    int i = (bid >> 3) * 64 + nlocal;
    if (i >= N) return;

    int beg = offsets[i], end = offsets[i + 1];
    float dvh = dv[i * 4 + head];
    const ushort* gbase = hbT + (size_t)c * Mpad * 32 + chunk * 8;

    f32x2 ax[4] = {};
    float den = 0.f;

    int k = beg;
    int sA = 0; float vA = 0.f; uint4 qA; qA.x = 0u; qA.y = 0u; qA.z = 0u; qA.w = 0u;
    if (k < end) {
        sA = srcs[k];
        vA = sv[sA * 4 + head];
        qA = *(const uint4*)(gbase + (size_t)sA * 32);
    }
    while (k < end) {
        int kn = k + 1;
        int sB = 0; float vB = 0.f; uint4 qB; qB.x = 0u; qB.y = 0u; qB.z = 0u; qB.w = 0u;
        if (kn < end) {
            sB = srcs[kn];
            vB = sv[sB * 4 + head];
            qB = *(const uint4*)(gbase + (size_t)sB * 32);
        }
        float e = vA + dvh;
        float wgt = __expf(fminf(fmaxf(e, NEG_SLOPE * e), 60.f));
        den += wgt;
        ACCUMW4(qA, wgt);
        k = kn; sA = sB; vA = vB; qA = qB;
    }

    // self edge + normalize + bias; each thread stores its 16B
    float e_self = sv[i * 4 + head] + dvh;
    float wself = __expf(fminf(fmaxf(e_self, NEG_SLOPE * e_self), 60.f));
    uint4 qs = *(const uint4*)(gbase + (size_t)i * 32);
    ACCUMW4(qs, wself);
    float rden = 1.f / (den + wself + 1e-16f);
    const float* bb = bias + c * 32 + chunk * 8;
    uint4 o;
    o.x = (uint)f2bf(ax[0].x * rden + bb[0]) | ((uint)f2bf(ax[0].y * rden + bb[1]) << 16);
    o.y = (uint)f2bf(ax[1].x * rden + bb[2]) | ((uint)f2bf(ax[1].y * rden + bb[3]) << 16);
    o.z = (uint)f2bf(ax[2].x * rden + bb[4]) | ((uint)f2bf(ax[2].y * rden + bb[5]) << 16);
    o.w = (uint)f2bf(ax[3].x * rden + bb[6]) | ((uint)f2bf(ax[3].y * rden + bb[7]) << 16);
    *(uint4*)&zb[(size_t)i * 256 + c * 32 + chunk * 8] = o;
}

// agg1 (H=1, 64ch): slice c = bid&7 (8ch = one 16B row); 256t = 256 nodes.
__launch_bounds__(256)
__global__ void agg1_kernel(const ushort* __restrict__ hbT, const float* __restrict__ sv,
                            const float* __restrict__ dv, const int* __restrict__ offsets,
                            const int* __restrict__ srcs, const float* __restrict__ bias,
                            ushort* __restrict__ zb, int N, int Mpad) {
    int t = threadIdx.x;
    int bid = blockIdx.x;
    int c = bid & 7;                    // slice
    int i = (bid >> 3) * 256 + t;
    if (i >= N) return;

    int beg = offsets[i], end = offsets[i + 1];
    float d_i = dv[i];
    const ushort* gbase = hbT + (size_t)c * Mpad * 8;

    f32x2 ax[4] = {};
    float den = 0.f;

    int k = beg;
    int sA = 0; float vA = 0.f; uint4 qA; qA.x = 0u; qA.y = 0u; qA.z = 0u; qA.w = 0u;
    if (k < end) {
        sA = srcs[k];
        vA = sv[sA];
        qA = *(const uint4*)(gbase + (size_t)sA * 8);
    }
    while (k < end) {
        int kn = k + 1;
        int sB = 0; float vB = 0.f; uint4 qB; qB.x = 0u; qB.y = 0u; qB.z = 0u; qB.w = 0u;
        if (kn < end) {
            sB = srcs[kn];
            vB = sv[sB];
            qB = *(const uint4*)(gbase + (size_t)sB * 8);
        }
        float e = vA + d_i;
        float wgt = __expf(fminf(fmaxf(e, NEG_SLOPE * e), 60.f));
        den += wgt;
        ACCUMW4(qA, wgt);
        k = kn; sA = sB; vA = vB; qA = qB;
    }

    float e_self = sv[i] + d_i;
    float wself = __expf(fminf(fmaxf(e_self, NEG_SLOPE * e_self), 60.f));
    uint4 qs = *(const uint4*)(gbase + (size_t)i * 8);
    ACCUMW4(qs, wself);
    float rden = 1.f / (den + wself + 1e-16f);
    const float* bb = bias + c * 8;
    uint4 o;
    o.x = (uint)f2bf(ax[0].x * rden + bb[0]) | ((uint)f2bf(ax[0].y * rden + bb[1]) << 16);
    o.y = (uint)f2bf(ax[1].x * rden + bb[2]) | ((uint)f2bf(ax[1].y * rden + bb[3]) << 16);
    o.z = (uint)f2bf(ax[2].x * rden + bb[4]) | ((uint)f2bf(ax[2].y * rden + bb[5]) << 16);
    o.w = (uint)f2bf(ax[3].x * rden + bb[6]) | ((uint)f2bf(ax[3].y * rden + bb[7]) << 16);
    *(uint4*)&zb[(size_t)i * 64 + c * 8] = o;
}

// ---------------- BatchNorm stats: vectorized grid-stride partials ----------------

template <int F>
__launch_bounds__(256)
__global__ void bn_stats_kernel(const ushort* __restrict__ x, float* __restrict__ ps,
                                float* __restrict__ pq, int N) {
    constexpr int OCT = F / 8;
    __shared__ float lds_s[F], lds_q[F];
    int t = threadIdx.x;
    if (t < F) { lds_s[t] = 0.f; lds_q[t] = 0.f; }
    __syncthreads();

    float s[8] = {}, q[8] = {};
    int total8 = N * F / 8;
    for (int idx = blockIdx.x * 256 + t; idx < total8; idx += NB_RED * 256) {
        uint4 v = ((const uint4*)x)[idx];
        uint pr[4] = {v.x, v.y, v.z, v.w};
#pragma unroll
        for (int k = 0; k < 4; ++k) {
            float a = bf2f(pr[k] & 0xffffu);
            float b = bf2f(pr[k] >> 16);
            s[2 * k] += a;     q[2 * k] += a * a;
            s[2 * k + 1] += b; q[2 * k + 1] += b * b;
        }
    }
    int co = t % OCT;
#pragma unroll
    for (int j = 0; j < 8; ++j) {
        atomicAdd(&lds_s[co * 8 + j], s[j]);
        atomicAdd(&lds_q[co * 8 + j], q[j]);
    }
    __syncthreads();
    if (t < F) {
        ps[blockIdx.x * F + t] = lds_s[t];
        pq[blockIdx.x * F + t] = lds_q[t];
    }
}

__global__ void bn_final_kernel(const float* __restrict__ ps, const float* __restrict__ pq,
                                const float* __restrict__ g, const float* __restrict__ be,
                                float* __restrict__ scale, float* __restrict__ shift,
                                int N, int F) {
    int t = threadIdx.x;
    if (t < F) {
        float s = 0.f, q = 0.f;
        for (int b = 0; b < NB_RED; ++b) { s += ps[b * F + t]; q += pq[b * F + t]; }
        float mean = s / (float)N;
        float var = q / (float)N - mean * mean;
        float sc = g[t] * rsqrtf(var + BN_EPS);
        scale[t] = sc;
        shift[t] = be[t] - sc * mean;
    }
}

__global__ void bn_apply_kernel(uint* __restrict__ x, const float* __restrict__ scale,
                                const float* __restrict__ shift, int totalPairs, int Fmask) {
    int i = blockIdx.x * blockDim.x + threadIdx.x;
    if (i < totalPairs) {
        uint p = x[i];
        int c0 = (2 * i) & Fmask;
        float v0 = fmaxf(bf2f(p & 0xffffu) * scale[c0] + shift[c0], 0.f);
        float v1 = fmaxf(bf2f(p >> 16) * scale[c0 + 1] + shift[c0 + 1], 0.f);
        x[i] = (uint)f2bf(v0) | ((uint)f2bf(v1) << 16);
    }
}

// ---------------- pooling (BN+ReLU fused, vectorized) ----------------

__launch_bounds__(256)
__global__ void pool_kernel(const ushort* __restrict__ y, const float* __restrict__ scale,
                            const float* __restrict__ shift, float* __restrict__ psum,
                            float* __restrict__ pmax, int N) {
    constexpr int F = 64, OCT = 8;
    __shared__ float lds_s[F];
    __shared__ uint lds_m[F];
    int t = threadIdx.x;
    if (t < F) { lds_s[t] = 0.f; lds_m[t] = 0u; }
    __syncthreads();

    int co = t % OCT;
    float sc[8], sh[8];
#pragma unroll
    for (int j = 0; j < 8; ++j) { sc[j] = scale[co * 8 + j]; sh[j] = shift[co * 8 + j]; }

    float s[8] = {}, m[8] = {};
    int total8 = N * F / 8;
    for (int idx = blockIdx.x * 256 + t; idx < total8; idx += NB_RED * 256) {
        uint4 v = ((const uint4*)y)[idx];
        uint pr[4] = {v.x, v.y, v.z, v.w};
#pragma unroll
        for (int k = 0; k < 4; ++k) {
            float a = fmaxf(bf2f(pr[k] & 0xffffu) * sc[2 * k] + sh[2 * k], 0.f);
            float b = fmaxf(bf2f(pr[k] >> 16) * sc[2 * k + 1] + sh[2 * k + 1], 0.f);
            s[2 * k] += a;     m[2 * k] = fmaxf(m[2 * k], a);
            s[2 * k + 1] += b; m[2 * k + 1] = fmaxf(m[2 * k + 1], b);
        }
    }
#pragma unroll
    for (int j = 0; j < 8; ++j) {
        atomicAdd(&lds_s[co * 8 + j], s[j]);
        atomicMax(&lds_m[co * 8 + j], __float_as_uint(m[j]));
    }
    __syncthreads();
    if (t < F) {
        psum[blockIdx.x * F + t] = lds_s[t];
        pmax[blockIdx.x * F + t] = __uint_as_float(lds_m[t]);
    }
}

__global__ void classify_kernel(const float* __restrict__ psum, const float* __restrict__ pmax,
                                const float* __restrict__ Wc1, const float* __restrict__ bc1,
                                const float* __restrict__ Wc2, const float* __restrict__ bc2,
                                float* __restrict__ out, int N) {
    __shared__ float pooled[128];
    __shared__ float z[64];
    int t = threadIdx.x;   // 128 threads
    if (t < 64) {
        float s = 0.f;
        for (int b = 0; b < NB_RED; ++b) s += psum[b * 64 + t];
        pooled[t] = s / (float)N;
    } else {
        int c = t - 64;
        float m = 0.f;
        for (int b = 0; b < NB_RED; ++b) m = fmaxf(m, pmax[b * 64 + c]);
        pooled[t] = m;
    }
    __syncthreads();
    if (t < 64) {
        float a = bc1[t];
        for (int k = 0; k < 128; ++k) a += pooled[k] * Wc1[k * 64 + t];
        z[t] = a > 0.f ? a : 0.f;
    }
    __syncthreads();
    if (t < 2) {
        float a = bc2[t];
        for (int j = 0; j < 64; ++j) a += z[j] * Wc2[j * 2 + t];
        out[t] = a;
    }
}

// ---------------- driver ----------------

extern "C" void kernel_launch(void* const* d_in, const int* in_sizes, int n_in,
                              void* d_out, int out_size, void* d_ws, size_t ws_size,
                              hipStream_t stream) {
    const float* x   = (const float*)d_in[0];
    const int*   ei  = (const int*)d_in[1];
    const float* W0  = (const float*)d_in[2];  const float* b0  = (const float*)d_in[3];
    const float* as0 = (const float*)d_in[4];  const float* ad0 = (const float*)d_in[5];
    const float* g0  = (const float*)d_in[6];  const float* be0 = (const float*)d_in[7];
    const float* W1  = (const float*)d_in[8];  const float* b1  = (const float*)d_in[9];
    const float* as1 = (const float*)d_in[10]; const float* ad1 = (const float*)d_in[11];
    const float* g1  = (const float*)d_in[12]; const float* be1 = (const float*)d_in[13];
    const float* W2  = (const float*)d_in[14]; const float* b2  = (const float*)d_in[15];
    const float* as2 = (const float*)d_in[16]; const float* ad2 = (const float*)d_in[17];
    const float* g2  = (const float*)d_in[18]; const float* be2 = (const float*)d_in[19];
    const float* Wc1 = (const float*)d_in[20]; const float* bc1 = (const float*)d_in[21];
    const float* Wc2 = (const float*)d_in[22]; const float* bc2 = (const float*)d_in[23];
    float* out = (float*)d_out;

    const int N = in_sizes[0] / 128;            // 50000
    const int E = in_sizes[1] / 2;              // 800000
    const int Mpad = ((N + 127) / 128) * 128;   // 50048
    const int NB_SCAN = (N + 1023) / 1024;      // 49
    const int NBROW = Mpad / 128;               // 391
    const int NB_A4 = ((N + 63) / 64) * 8;      // 6256 (64 nodes/block x 8 slices)
    const int NB_A1 = ((N + 255) / 256) * 8;    // 1568 (256 nodes/block x 8 slices)

    char* ws = (char*)d_ws;
    size_t o = 0;
    auto alloc = [&](size_t bytes) -> void* {
        void* p = ws + o;
        o = (o + bytes + 255) & ~(size_t)255;
        return p;
    };
    int*    deg     = (int*)alloc((size_t)N * 4);
    int*    offsets = (int*)alloc((size_t)(N + 1) * 4);
    int*    cursor  = (int*)alloc((size_t)N * 4);
    int*    srcs    = (int*)alloc((size_t)E * 4);
    int*    bsum    = (int*)alloc((size_t)NB_SCAN * 4);
    int*    bexcl   = (int*)alloc((size_t)NB_SCAN * 4);
    ushort* xb      = (ushort*)alloc((size_t)Mpad * 128 * 2);
    ushort* w0t     = (ushort*)alloc((size_t)256 * 128 * 2);
    ushort* w1t     = (ushort*)alloc((size_t)256 * 256 * 2);
    ushort* w2t     = (ushort*)alloc((size_t)64 * 256 * 2);
    ushort* hb      = (ushort*)alloc((size_t)Mpad * 256 * 2);   // sliced [8][Mpad][32] ([8][Mpad][8] for L2)
    ushort* zb      = (ushort*)alloc((size_t)Mpad * 256 * 2);   // normal [node][ch]
    float*  sv      = (float*)alloc((size_t)Mpad * 4 * 4);
    float*  dv      = (float*)alloc((size_t)Mpad * 4 * 4);
    float*  ps      = (float*)alloc((size_t)NB_RED * 256 * 4);
    float*  pq      = (float*)alloc((size_t)NB_RED * 256 * 4);
    float*  scale   = (float*)alloc(256 * 4);
    float*  shift   = (float*)alloc(256 * 4);
    float*  psum    = (float*)alloc((size_t)NB_RED * 64 * 4);
    float*  pmax    = (float*)alloc((size_t)NB_RED * 64 * 4);

    // ---- prep (cvt + transpose + histogram) ----
    (void)hipMemsetAsync(deg, 0, (size_t)N * 4, stream);
    int prep_total = Mpad * 128 + 32768 + 65536 + 16384 + E;
    prep_kernel<<<(prep_total + 255) / 256, 256, 0, stream>>>(
        x, xb, N * 128, Mpad * 128, W0, w0t, W1, w1t, W2, w2t, ei, deg, E);

    // ---- CSR scan + scatter ----
    scan_part<<<NB_SCAN, 256, 0, stream>>>(deg, offsets, bsum, N);
    scan_top<<<1, 64, 0, stream>>>(bsum, bexcl, NB_SCAN, offsets, N);
    scan_add<<<NB_SCAN, 256, 0, stream>>>(offsets, cursor, bexcl, N);
    scatter_kernel<<<(E + 255) / 256, 256, 0, stream>>>(ei, cursor, srcs, E);

    // ---- layer 0 ----
    {
        mfma_gemm_bt<128, 4><<<NBROW * 2, 256, 0, stream>>>(xb, w0t, hb, as0, ad0, sv, dv,
                                                            128, 256, Mpad);
        agg4_kernel<<<NB_A4, 256, 0, stream>>>(hb, sv, dv, offsets, srcs, b0, zb, N, Mpad);
        bn_stats_kernel<256><<<NB_RED, 256, 0, stream>>>(zb, ps, pq, N);
        bn_final_kernel<<<1, 256, 0, stream>>>(ps, pq, g0, be0, scale, shift, N, 256);
        bn_apply_kernel<<<(N * 128 + 255) / 256, 256, 0, stream>>>((uint*)zb, scale, shift,
                                                                   N * 128, 255);
    }
    // ---- layer 1 ----
    {
        mfma_gemm_bt<128, 4><<<NBROW * 2, 256, 0, stream>>>(zb, w1t, hb, as1, ad1, sv, dv,
                                                            256, 256, Mpad);
        agg4_kernel<<<NB_A4, 256, 0, stream>>>(hb, sv, dv, offsets, srcs, b1, zb, N, Mpad);
        bn_stats_kernel<256><<<NB_RED, 256, 0, stream>>>(zb, ps, pq, N);
        bn_final_kernel<<<1, 256, 0, stream>>>(ps, pq, g1, be1, scale, shift, N, 256);
        bn_apply_kernel<<<(N * 128 + 255) / 256, 256, 0, stream>>>((uint*)zb, scale, shift,
                                                                   N * 128, 255);
    }
    // ---- layer 2 (1 head, F=64); BN-apply fused into pool ----
    {
        mfma_gemm_bt<64, 1><<<NBROW, 256, 0, stream>>>(zb, w2t, hb, as2, ad2, sv, dv,
                                                       256, 64, Mpad);
        agg1_kernel<<<NB_A1, 256, 0, stream>>>(hb, sv, dv, offsets, srcs, b2, zb, N, Mpad);
        bn_stats_kernel<64><<<NB_RED, 256, 0, stream>>>(zb, ps, pq, N);
        bn_final_kernel<<<1, 64, 0, stream>>>(ps, pq, g2, be2, scale, shift, N, 64);
    }

    // ---- pooling (BN+ReLU fused) + classifier ----
    pool_kernel<<<NB_RED, 256, 0, stream>>>(zb, scale, shift, psum, pmax, N);
    classify_kernel<<<1, 128, 0, stream>>>(psum, pmax, Wc1, bc1, Wc2, bc2, out, N);
}

// Round 23
// 584.694 us; speedup vs baseline: 1.2237x; 1.2237x over previous
//
#include <hip/hip_runtime.h>

// ---------------------------------------------------------------------------
// GAT fraud detector, round 12 (resubmit — rounds 20-22 hit GPUAcquisitionTimeout):
//  REVERT to best-measured config (r6 = 585.0us, measured round 2).
//  Session record on agg: non-sliced variants r5/r6/r7b/r8 = 65.8/67.0/68.3/
//  67.5us, all pinned at the 205MB 8-XCD compulsory fill (~3.5 TB/s).
//  Channel-sliced variants r9/r10/r11 = 85/68(+40 wgt)/106us — byte cut
//  (205->82MB) confirmed but each implementation paid more in VALU
//  replication / wave tax / serial-chain latency. agg is AT ITS FLOOR.
//  This is the r6 kernel verbatim: depth-2-pair pipelined agg (stride-9
//  padded lsum), MFMA GEMM + fused sd + XCD-pair swizzle, parallel scan,
//  vectorized BN/pool partials.
// ---------------------------------------------------------------------------

typedef unsigned int uint;
typedef unsigned short ushort;

#define NEG_SLOPE 0.2f
#define BN_EPS 1e-5f
#define NB_RED 256   // blocks for BN-stats / pool partial reductions

typedef __attribute__((ext_vector_type(2))) float f32x2;

__device__ __forceinline__ float bf2f(uint u) { return __uint_as_float(u << 16); }
__device__ __forceinline__ ushort f2bf(float f) {
    uint u = __float_as_uint(f);
    u += 0x7fff + ((u >> 16) & 1);   // round-nearest-even
    return (ushort)(u >> 16);
}

// ---------------- fused prep: cvt x -> bf16 (padded), transpose weights, histogram ----------------

__global__ void prep_kernel(const float* __restrict__ x, ushort* __restrict__ xb,
                            int total_real, int total_pad,
                            const float* __restrict__ W0, ushort* __restrict__ w0t,
                            const float* __restrict__ W1, ushort* __restrict__ w1t,
                            const float* __restrict__ W2, ushort* __restrict__ w2t,
                            const int* __restrict__ ei, int* __restrict__ deg, int E) {
    int i = blockIdx.x * blockDim.x + threadIdx.x;
    if (i < total_pad) {
        xb[i] = (i < total_real) ? f2bf(x[i]) : (ushort)0;
        return;
    }
    int j = i - total_pad;
    if (j < 32768) {                        // W0: K=128,F=256
        int n = j / 128, k = j - n * 128;
        w0t[j] = f2bf(W0[(size_t)k * 256 + n]);
        return;
    }
    j -= 32768;
    if (j < 65536) {                        // W1: K=256,F=256
        int n = j / 256, k = j - n * 256;
        w1t[j] = f2bf(W1[(size_t)k * 256 + n]);
        return;
    }
    j -= 65536;
    if (j < 16384) {                        // W2: K=256,F=64
        int n = j / 256, k = j - n * 256;
        w2t[j] = f2bf(W2[(size_t)k * 64 + n]);
        return;
    }
    j -= 16384;
    if (j < E) atomicAdd(&deg[ei[E + j]], 1);
}

// ---------------- CSR scan + scatter ----------------

__global__ void scan_part(const int* __restrict__ deg, int* __restrict__ offsets,
                          int* __restrict__ bsum, int N) {
    __shared__ int sh[256];
    int t = threadIdx.x;
    int base = blockIdx.x * 1024 + t * 4;
    int v0 = (base + 0 < N) ? deg[base + 0] : 0;
    int v1 = (base + 1 < N) ? deg[base + 1] : 0;
    int v2 = (base + 2 < N) ? deg[base + 2] : 0;
    int v3 = (base + 3 < N) ? deg[base + 3] : 0;
    int s = v0 + v1 + v2 + v3;
    sh[t] = s;
    __syncthreads();
    for (int off = 1; off < 256; off <<= 1) {
        int y = (t >= off) ? sh[t - off] : 0;
        __syncthreads();
        sh[t] += y;
        __syncthreads();
    }
    int p = sh[t] - s;
    if (base + 0 < N) offsets[base + 0] = p;
    p += v0;
    if (base + 1 < N) offsets[base + 1] = p;
    p += v1;
    if (base + 2 < N) offsets[base + 2] = p;
    p += v2;
    if (base + 3 < N) offsets[base + 3] = p;
    if (t == 255) bsum[blockIdx.x] = sh[255];
}

__global__ void scan_top(const int* __restrict__ bsum, int* __restrict__ bexcl,
                         int nb, int* __restrict__ offsets, int N) {
    if (threadIdx.x == 0) {
        int run = 0;
        for (int b = 0; b < nb; ++b) { bexcl[b] = run; run += bsum[b]; }
        offsets[N] = run;
    }
}

__global__ void scan_add(int* __restrict__ offsets, int* __restrict__ cursor,
                         const int* __restrict__ bexcl, int N) {
    int add = bexcl[blockIdx.x];
    int base = blockIdx.x * 1024 + threadIdx.x * 4;
#pragma unroll
    for (int k = 0; k < 4; ++k) {
        int i = base + k;
        if (i < N) { int v = offsets[i] + add; offsets[i] = v; cursor[i] = v; }
    }
}

__global__ void scatter_kernel(const int* __restrict__ ei, int* __restrict__ cursor,
                               int* __restrict__ srcs, int E) {
    int e = blockIdx.x * blockDim.x + threadIdx.x;
    if (e < E) {
        int s = ei[e];
        int d = ei[E + e];
        int p = atomicAdd(&cursor[d], 1);
        srcs[p] = s;
    }
}

// ---------------- bf16 MFMA GEMM with fused sd epilogue ----------------

typedef __attribute__((ext_vector_type(8))) short bf16x8;
typedef __attribute__((ext_vector_type(4))) float floatx4;

template <int BN, int H>
__launch_bounds__(256)
__global__ void mfma_gemm_bt(const ushort* __restrict__ A, const ushort* __restrict__ Bt,
                             ushort* __restrict__ C, const float* __restrict__ asrc,
                             const float* __restrict__ adst, float* __restrict__ sv,
                             float* __restrict__ dv, int K, int Nn) {
    constexpr int WCOLS = (BN == 128) ? 2 : 1;
    constexpr int WROWS = 4 / WCOLS;
    constexpr int MT = 128 / (WROWS * 16);
    constexpr int NT = BN / (WCOLS * 16);
    constexpr int BCALLS = (BN * 32 * 2) / 4096;

    __shared__ ushort As[128 * 32];
    __shared__ ushort Bs[BN * 32];

    int t = threadIdx.x;
    int w = t >> 6, l = t & 63;

    // block -> tile mapping. For the 2-column-block layers (BN==128), use a
    // 1D grid with an XCD-pairing swizzle: ids d and d+8 are (same row tile,
    // col 0/1) and share d%8 -> same XCD L2 -> second A-panel read is L2-hit.
    int rb, cb;
    if (BN == 128) {
        int nbr = (int)gridDim.x >> 1;       // row tiles
        int full = (nbr & ~7) << 1;
        int id = blockIdx.x;
        if (id < full) {
            rb = ((id >> 4) << 3) + (id & 7);
            cb = (id >> 3) & 1;
        } else {
            int o = id - full;
            int rem = nbr & 7;
            rb = (nbr & ~7) + (rem ? (o % rem) : 0);
            cb = rem ? (o / rem) : 0;
        }
    } else {
        rb = blockIdx.x;
        cb = 0;
    }
    int row0 = rb * 128;
    int col0 = cb * BN;
    int wr = (w / WCOLS) * (MT * 16);
    int wc = (w % WCOLS) * (NT * 16);

    floatx4 acc[MT][NT];
#pragma unroll
    for (int mi = 0; mi < MT; ++mi)
#pragma unroll
        for (int ni = 0; ni < NT; ++ni)
#pragma unroll
            for (int r = 0; r < 4; ++r) acc[mi][ni][r] = 0.f;

    int mrow = l & 15;
    int kc = (l >> 4) * 8;

    for (int kt = 0; kt < K; kt += 32) {
#pragma unroll
        for (int c = 0; c < 2; ++c) {
            int idx = c * 256 + t;
            const ushort* gp = A + (size_t)(row0 + (idx >> 2)) * K + kt + (idx & 3) * 8;
            __builtin_amdgcn_global_load_lds(
                (const __attribute__((address_space(1))) void*)gp,
                (__attribute__((address_space(3))) void*)(As + (idx & ~63) * 8),
                16, 0, 0);
        }
#pragma unroll
        for (int c = 0; c < BCALLS; ++c) {
            int idx = c * 256 + t;
            const ushort* gp = Bt + (size_t)(col0 + (idx >> 2)) * K + kt + (idx & 3) * 8;
            __builtin_amdgcn_global_load_lds(
                (const __attribute__((address_space(1))) void*)gp,
                (__attribute__((address_space(3))) void*)(Bs + (idx & ~63) * 8),
                16, 0, 0);
        }
        __syncthreads();

        bf16x8 af[MT], bfr[NT];
#pragma unroll
        for (int mi = 0; mi < MT; ++mi)
            af[mi] = *(const bf16x8*)&As[(wr + mi * 16 + mrow) * 32 + kc];
#pragma unroll
        for (int ni = 0; ni < NT; ++ni)
            bfr[ni] = *(const bf16x8*)&Bs[(wc + ni * 16 + mrow) * 32 + kc];
#pragma unroll
        for (int mi = 0; mi < MT; ++mi)
#pragma unroll
            for (int ni = 0; ni < NT; ++ni)
                acc[mi][ni] = __builtin_amdgcn_mfma_f32_16x16x32_bf16(
                    af[mi], bfr[ni], acc[mi][ni], 0, 0, 0);
        __syncthreads();
    }

    // C store (C/D layout: col=lane&15, row=(lane>>4)*4+reg)
#pragma unroll
    for (int mi = 0; mi < MT; ++mi) {
        int rbase = row0 + wr + mi * 16 + (l >> 4) * 4;
#pragma unroll
        for (int ni = 0; ni < NT; ++ni) {
            int col = col0 + wc + ni * 16 + (l & 15);
#pragma unroll
            for (int r = 0; r < 4; ++r)
                C[(size_t)(rbase + r) * Nn + col] = f2bf(acc[mi][ni][r]);
        }
    }

    // fused sd: this wave's NT*16 cols lie in exactly one head (64 cols).
    float av[NT], bv[NT];
#pragma unroll
    for (int ni = 0; ni < NT; ++ni) {
        int ch = col0 + wc + ni * 16 + (l & 15);
        av[ni] = asrc[ch];
        bv[ni] = adst[ch];
    }
    int gh = (col0 + wc) >> 6;
#pragma unroll
    for (int mi = 0; mi < MT; ++mi) {
#pragma unroll
        for (int r = 0; r < 4; ++r) {
            float s = 0.f, d = 0.f;
#pragma unroll
            for (int ni = 0; ni < NT; ++ni) {
                float hv = acc[mi][ni][r];
                s += hv * av[ni];
                d += hv * bv[ni];
            }
#pragma unroll
            for (int m = 8; m >= 1; m >>= 1) {
                s += __shfl_xor(s, m);
                d += __shfl_xor(d, m);
            }
            if ((l & 15) == 0) {
                int row = row0 + wr + mi * 16 + (l >> 4) * 4 + r;
                sv[row * H + gh] = s;
                dv[row * H + gh] = d;
            }
        }
    }
}

// ---------------- single-pass softmax aggregation, 4-way edge-parallel ----------------
// 128 threads = 4 groups x 32 lanes. Group g handles edges beg+g, beg+g+4, ...
// Lane gl owns 8 channels [gl*8, gl*8+8) -> one uint4 (16B) load per edge.
// Software-pipelined: edges j+8/j+12 prefetched while computing j/j+4, so
// 2-4 row loads are in flight per group (was 1 dependent load per iter).
// lsum padded stride-9 (idx = ch + (ch>>3)): conflict-free stores (9 coprime 32).

#define ACCUM4(q, s) { \
    float e_ = (s) + d_i; \
    float w_ = __expf(fminf(fmaxf(e_, NEG_SLOPE * e_), 60.f)); \
    den += w_; \
    f32x2 wv_ = {w_, w_}; \
    uint pr_[4] = {(q).x, (q).y, (q).z, (q).w}; \
    _Pragma("unroll") \
    for (int k_ = 0; k_ < 4; ++k_) { \
        f32x2 hv_ = {__uint_as_float(pr_[k_] << 16), \
                     __uint_as_float(pr_[k_] & 0xffff0000u)}; \
        ax[k_] += wv_ * hv_; \
    } }

__launch_bounds__(128)
__global__ void agg4_kernel(const ushort* __restrict__ hb, const float* __restrict__ sv,
                            const float* __restrict__ dv, const int* __restrict__ offsets,
                            const int* __restrict__ srcs, const float* __restrict__ bias,
                            ushort* __restrict__ zb, int N) {
    __shared__ float lsum[4][288];    // idx = ch + (ch>>3), max 255+31=286
    __shared__ float lden[4][4];

    int i = blockIdx.x;
    int t = threadIdx.x;
    int grp = t >> 5, gl = t & 31;
    int head = gl >> 3;                 // head of this lane's channels
    int beg = offsets[i], end = offsets[i + 1];

    float d_i = dv[i * 4 + head];
    f32x2 ax[4] = {};                   // channels {gl*8+2k, gl*8+2k+1}
    float den = 0.f;

    const ushort* hrow = hb + gl * 8;   // + srcn*256

    int j = beg + grp;
    float sA = 0.f, sB = 0.f;
    uint4 qA = {0, 0, 0, 0}, qB = {0, 0, 0, 0};
    if (j < end) {
        int n = srcs[j];
        sA = sv[n * 4 + head];
        qA = *(const uint4*)(hrow + (size_t)n * 256);
    }
    if (j + 4 < end) {
        int n = srcs[j + 4];
        sB = sv[n * 4 + head];
        qB = *(const uint4*)(hrow + (size_t)n * 256);
    }

    while (j + 4 < end) {
        int jc = j + 8, jd = j + 12;
        float sC = 0.f, sD = 0.f;
        uint4 qC = {0, 0, 0, 0}, qD = {0, 0, 0, 0};
        if (jc < end) {
            int n = srcs[jc];
            sC = sv[n * 4 + head];
            qC = *(const uint4*)(hrow + (size_t)n * 256);
        }
        if (jd < end) {
            int n = srcs[jd];
            sD = sv[n * 4 + head];
            qD = *(const uint4*)(hrow + (size_t)n * 256);
        }
        ACCUM4(qA, sA);
        ACCUM4(qB, sB);
        sA = sC; qA = qC;
        sB = sD; qB = qD;
        j += 8;
    }
    if (j < end) ACCUM4(qA, sA);

#pragma unroll
    for (int k = 0; k < 4; ++k) {
        lsum[grp][gl * 9 + 2 * k]     = ax[k].x;
        lsum[grp][gl * 9 + 2 * k + 1] = ax[k].y;
    }
    if ((gl & 7) == 0) lden[grp][head] = den;
    __syncthreads();

    // final: thread t owns channels {2t, 2t+1}; head = t>>5
    int h = t >> 5;
    float e_self = sv[i * 4 + h] + dv[i * 4 + h];
    float wself = __expf(fminf(fmaxf(e_self, NEG_SLOPE * e_self), 60.f));
    float dtot = lden[0][h] + lden[1][h] + lden[2][h] + lden[3][h] + wself + 1e-16f;
    float rden = 1.f / dtot;
    int idx = 2 * t + (t >> 2);     // = ch0 + (ch0>>3)
    uint p = *(const uint*)&hb[(size_t)i * 256 + 2 * t];
    float a0 = lsum[0][idx] + lsum[1][idx] + lsum[2][idx] + lsum[3][idx]
             + wself * __uint_as_float(p << 16);
    float a1 = lsum[0][idx + 1] + lsum[1][idx + 1] + lsum[2][idx + 1]
             + lsum[3][idx + 1] + wself * __uint_as_float(p & 0xffff0000u);
    a0 = a0 * rden + bias[2 * t];
    a1 = a1 * rden + bias[2 * t + 1];
    *(uint*)&zb[(size_t)i * 256 + 2 * t] = (uint)f2bf(a0) | ((uint)f2bf(a1) << 16);
}

// H=1, 64 channels: 64 threads = 4 groups x 16 lanes, uint2 (4ch) per lane,
// cross-group combine via in-wave shuffles. Same depth-2-pair pipeline.

#define ACCUM1(q, s) { \
    float e_ = (s) + d_i; \
    float w_ = __expf(fminf(fmaxf(e_, NEG_SLOPE * e_), 60.f)); \
    den += w_; \
    f32x2 wv_ = {w_, w_}; \
    f32x2 h0_ = {__uint_as_float((q).x << 16), __uint_as_float((q).x & 0xffff0000u)}; \
    f32x2 h1_ = {__uint_as_float((q).y << 16), __uint_as_float((q).y & 0xffff0000u)}; \
    ax[0] += wv_ * h0_; \
    ax[1] += wv_ * h1_; }

__launch_bounds__(64)
__global__ void agg1_kernel(const ushort* __restrict__ hb, const float* __restrict__ sv,
                            const float* __restrict__ dv, const int* __restrict__ offsets,
                            const int* __restrict__ srcs, const float* __restrict__ bias,
                            ushort* __restrict__ zb, int N) {
    int i = blockIdx.x;
    int l = threadIdx.x;
    int grp = l >> 4, gl = l & 15;
    int beg = offsets[i], end = offsets[i + 1];

    float d_i = dv[i];
    f32x2 ax[2] = {};
    float den = 0.f;

    const ushort* hrow = hb + gl * 4;   // + srcn*64

    int j = beg + grp;
    float sA = 0.f, sB = 0.f;
    uint2 qA = {0, 0}, qB = {0, 0};
    if (j < end) {
        int n = srcs[j];
        sA = sv[n];
        qA = *(const uint2*)(hrow + (size_t)n * 64);
    }
    if (j + 4 < end) {
        int n = srcs[j + 4];
        sB = sv[n];
        qB = *(const uint2*)(hrow + (size_t)n * 64);
    }

    while (j + 4 < end) {
        int jc = j + 8, jd = j + 12;
        float sC = 0.f, sD = 0.f;
        uint2 qC = {0, 0}, qD = {0, 0};
        if (jc < end) {
            int n = srcs[jc];
            sC = sv[n];
            qC = *(const uint2*)(hrow + (size_t)n * 64);
        }
        if (jd < end) {
            int n = srcs[jd];
            sD = sv[n];
            qD = *(const uint2*)(hrow + (size_t)n * 64);
        }
        ACCUM1(qA, sA);
        ACCUM1(qB, sB);
        sA = sC; qA = qC;
        sB = sD; qB = qD;
        j += 8;
    }
    if (j < end) ACCUM1(qA, sA);

    float a4[4] = {ax[0].x, ax[0].y, ax[1].x, ax[1].y};
    // combine the 4 groups (lanes l, l^16, l^32, l^48)
#pragma unroll
    for (int k = 0; k < 4; ++k) {
        a4[k] += __shfl_xor(a4[k], 16);
        a4[k] += __shfl_xor(a4[k], 32);
    }
    den += __shfl_xor(den, 16);
    den += __shfl_xor(den, 32);

    if (l < 16) {
        float e_self = sv[i] + d_i;
        float wself = __expf(fminf(fmaxf(e_self, NEG_SLOPE * e_self), 60.f));
        float rden = 1.f / (den + wself + 1e-16f);
        uint2 q = *(const uint2*)&hb[(size_t)i * 64 + gl * 4];
        float a0 = (a4[0] + wself * bf2f(q.x & 0xffffu)) * rden + bias[gl * 4 + 0];
        float a1 = (a4[1] + wself * bf2f(q.x >> 16)) * rden + bias[gl * 4 + 1];
        float a2 = (a4[2] + wself * bf2f(q.y & 0xffffu)) * rden + bias[gl * 4 + 2];
        float a3 = (a4[3] + wself * bf2f(q.y >> 16)) * rden + bias[gl * 4 + 3];
        uint2 o;
        o.x = (uint)f2bf(a0) | ((uint)f2bf(a1) << 16);
        o.y = (uint)f2bf(a2) | ((uint)f2bf(a3) << 16);
        *(uint2*)&zb[(size_t)i * 64 + gl * 4] = o;
    }
}

// ---------------- BatchNorm stats: vectorized grid-stride partials ----------------

template <int F>
__launch_bounds__(256)
__global__ void bn_stats_kernel(const ushort* __restrict__ x, float* __restrict__ ps,
                                float* __restrict__ pq, int N) {
    constexpr int OCT = F / 8;
    __shared__ float lds_s[F], lds_q[F];
    int t = threadIdx.x;
    if (t < F) { lds_s[t] = 0.f; lds_q[t] = 0.f; }
    __syncthreads();

    float s[8] = {}, q[8] = {};
    int total8 = N * F / 8;
    for (int idx = blockIdx.x * 256 + t; idx < total8; idx += NB_RED * 256) {
        uint4 v = ((const uint4*)x)[idx];
        uint pr[4] = {v.x, v.y, v.z, v.w};
#pragma unroll
        for (int k = 0; k < 4; ++k) {
            float a = bf2f(pr[k] & 0xffffu);
            float b = bf2f(pr[k] >> 16);
            s[2 * k] += a;     q[2 * k] += a * a;
            s[2 * k + 1] += b; q[2 * k + 1] += b * b;
        }
    }
    int co = t % OCT;
#pragma unroll
    for (int j = 0; j < 8; ++j) {
        atomicAdd(&lds_s[co * 8 + j], s[j]);
        atomicAdd(&lds_q[co * 8 + j], q[j]);
    }
    __syncthreads();
    if (t < F) {
        ps[blockIdx.x * F + t] = lds_s[t];
        pq[blockIdx.x * F + t] = lds_q[t];
    }
}

__global__ void bn_final_kernel(const float* __restrict__ ps, const float* __restrict__ pq,
                                const float* __restrict__ g, const float* __restrict__ be,
                                float* __restrict__ scale, float* __restrict__ shift,
                                int N, int F) {
    int t = threadIdx.x;
    if (t < F) {
        float s = 0.f, q = 0.f;
        for (int b = 0; b < NB_RED; ++b) { s += ps[b * F + t]; q += pq[b * F + t]; }
        float mean = s / (float)N;
        float var = q / (float)N - mean * mean;
        float sc = g[t] * rsqrtf(var + BN_EPS);
        scale[t] = sc;
        shift[t] = be[t] - sc * mean;
    }
}

__global__ void bn_apply_kernel(uint* __restrict__ x, const float* __restrict__ scale,
                                const float* __restrict__ shift, int totalPairs, int Fmask) {
    int i = blockIdx.x * blockDim.x + threadIdx.x;
    if (i < totalPairs) {
        uint p = x[i];
        int c0 = (2 * i) & Fmask;
        float v0 = fmaxf(bf2f(p & 0xffffu) * scale[c0] + shift[c0], 0.f);
        float v1 = fmaxf(bf2f(p >> 16) * scale[c0 + 1] + shift[c0 + 1], 0.f);
        x[i] = (uint)f2bf(v0) | ((uint)f2bf(v1) << 16);
    }
}

// ---------------- pooling (BN+ReLU fused, vectorized) ----------------

__launch_bounds__(256)
__global__ void pool_kernel(const ushort* __restrict__ y, const float* __restrict__ scale,
                            const float* __restrict__ shift, float* __restrict__ psum,
                            float* __restrict__ pmax, int N) {
    constexpr int F = 64, OCT = 8;
    __shared__ float lds_s[F];
    __shared__ uint lds_m[F];
    int t = threadIdx.x;
    if (t < F) { lds_s[t] = 0.f; lds_m[t] = 0u; }
    __syncthreads();

    int co = t % OCT;
    float sc[8], sh[8];
#pragma unroll
    for (int j = 0; j < 8; ++j) { sc[j] = scale[co * 8 + j]; sh[j] = shift[co * 8 + j]; }

    float s[8] = {}, m[8] = {};
    int total8 = N * F / 8;
    for (int idx = blockIdx.x * 256 + t; idx < total8; idx += NB_RED * 256) {
        uint4 v = ((const uint4*)y)[idx];
        uint pr[4] = {v.x, v.y, v.z, v.w};
#pragma unroll
        for (int k = 0; k < 4; ++k) {
            float a = fmaxf(bf2f(pr[k] & 0xffffu) * sc[2 * k] + sh[2 * k], 0.f);
            float b = fmaxf(bf2f(pr[k] >> 16) * sc[2 * k + 1] + sh[2 * k + 1], 0.f);
            s[2 * k] += a;     m[2 * k] = fmaxf(m[2 * k], a);
            s[2 * k + 1] += b; m[2 * k + 1] = fmaxf(m[2 * k + 1], b);
        }
    }
#pragma unroll
    for (int j = 0; j < 8; ++j) {
        atomicAdd(&lds_s[co * 8 + j], s[j]);
        atomicMax(&lds_m[co * 8 + j], __float_as_uint(m[j]));
    }
    __syncthreads();
    if (t < F) {
        psum[blockIdx.x * F + t] = lds_s[t];
        pmax[blockIdx.x * F + t] = __uint_as_float(lds_m[t]);
    }
}

__global__ void classify_kernel(const float* __restrict__ psum, const float* __restrict__ pmax,
                                const float* __restrict__ Wc1, const float* __restrict__ bc1,
                                const float* __restrict__ Wc2, const float* __restrict__ bc2,
                                float* __restrict__ out, int N) {
    __shared__ float pooled[128];
    __shared__ float z[64];
    int t = threadIdx.x;   // 128 threads
    if (t < 64) {
        float s = 0.f;
        for (int b = 0; b < NB_RED; ++b) s += psum[b * 64 + t];
        pooled[t] = s / (float)N;
    } else {
        int c = t - 64;
        float m = 0.f;
        for (int b = 0; b < NB_RED; ++b) m = fmaxf(m, pmax[b * 64 + c]);
        pooled[t] = m;
    }
    __syncthreads();
    if (t < 64) {
        float a = bc1[t];
        for (int k = 0; k < 128; ++k) a += pooled[k] * Wc1[k * 64 + t];
        z[t] = a > 0.f ? a : 0.f;
    }
    __syncthreads();
    if (t < 2) {
        float a = bc2[t];
        for (int j = 0; j < 64; ++j) a += z[j] * Wc2[j * 2 + t];
        out[t] = a;
    }
}

// ---------------- driver ----------------

extern "C" void kernel_launch(void* const* d_in, const int* in_sizes, int n_in,
                              void* d_out, int out_size, void* d_ws, size_t ws_size,
                              hipStream_t stream) {
    const float* x   = (const float*)d_in[0];
    const int*   ei  = (const int*)d_in[1];
    const float* W0  = (const float*)d_in[2];  const float* b0  = (const float*)d_in[3];
    const float* as0 = (const float*)d_in[4];  const float* ad0 = (const float*)d_in[5];
    const float* g0  = (const float*)d_in[6];  const float* be0 = (const float*)d_in[7];
    const float* W1  = (const float*)d_in[8];  const float* b1  = (const float*)d_in[9];
    const float* as1 = (const float*)d_in[10]; const float* ad1 = (const float*)d_in[11];
    const float* g1  = (const float*)d_in[12]; const float* be1 = (const float*)d_in[13];
    const float* W2  = (const float*)d_in[14]; const float* b2  = (const float*)d_in[15];
    const float* as2 = (const float*)d_in[16]; const float* ad2 = (const float*)d_in[17];
    const float* g2  = (const float*)d_in[18]; const float* be2 = (const float*)d_in[19];
    const float* Wc1 = (const float*)d_in[20]; const float* bc1 = (const float*)d_in[21];
    const float* Wc2 = (const float*)d_in[22]; const float* bc2 = (const float*)d_in[23];
    float* out = (float*)d_out;

    const int N = in_sizes[0] / 128;            // 50000
    const int E = in_sizes[1] / 2;              // 800000
    const int Mpad = ((N + 127) / 128) * 128;   // 50048
    const int NB_SCAN = (N + 1023) / 1024;      // 49
    const int NBROW = Mpad / 128;               // 391

    char* ws = (char*)d_ws;
    size_t o = 0;
    auto alloc = [&](size_t bytes) -> void* {
        void* p = ws + o;
        o = (o + bytes + 255) & ~(size_t)255;
        return p;
    };
    int*    deg     = (int*)alloc((size_t)N * 4);
    int*    offsets = (int*)alloc((size_t)(N + 1) * 4);
    int*    cursor  = (int*)alloc((size_t)N * 4);
    int*    srcs    = (int*)alloc((size_t)E * 4);
    int*    bsum    = (int*)alloc((size_t)NB_SCAN * 4);
    int*    bexcl   = (int*)alloc((size_t)NB_SCAN * 4);
    ushort* xb      = (ushort*)alloc((size_t)Mpad * 128 * 2);
    ushort* w0t     = (ushort*)alloc((size_t)256 * 128 * 2);
    ushort* w1t     = (ushort*)alloc((size_t)256 * 256 * 2);
    ushort* w2t     = (ushort*)alloc((size_t)64 * 256 * 2);
    ushort* hb      = (ushort*)alloc((size_t)Mpad * 256 * 2);
    ushort* zb      = (ushort*)alloc((size_t)Mpad * 256 * 2);
    float*  sv      = (float*)alloc((size_t)Mpad * 4 * 4);
    float*  dv      = (float*)alloc((size_t)Mpad * 4 * 4);
    float*  ps      = (float*)alloc((size_t)NB_RED * 256 * 4);
    float*  pq      = (float*)alloc((size_t)NB_RED * 256 * 4);
    float*  scale   = (float*)alloc(256 * 4);
    float*  shift   = (float*)alloc(256 * 4);
    float*  psum    = (float*)alloc((size_t)NB_RED * 64 * 4);
    float*  pmax    = (float*)alloc((size_t)NB_RED * 64 * 4);

    // ---- prep (cvt + transpose + histogram) ----
    (void)hipMemsetAsync(deg, 0, (size_t)N * 4, stream);
    int prep_total = Mpad * 128 + 32768 + 65536 + 16384 + E;
    prep_kernel<<<(prep_total + 255) / 256, 256, 0, stream>>>(
        x, xb, N * 128, Mpad * 128, W0, w0t, W1, w1t, W2, w2t, ei, deg, E);

    // ---- CSR scan + scatter ----
    scan_part<<<NB_SCAN, 256, 0, stream>>>(deg, offsets, bsum, N);
    scan_top<<<1, 64, 0, stream>>>(bsum, bexcl, NB_SCAN, offsets, N);
    scan_add<<<NB_SCAN, 256, 0, stream>>>(offsets, cursor, bexcl, N);
    scatter_kernel<<<(E + 255) / 256, 256, 0, stream>>>(ei, cursor, srcs, E);

    // ---- layer 0 ----
    {
        mfma_gemm_bt<128, 4><<<NBROW * 2, 256, 0, stream>>>(xb, w0t, hb, as0, ad0, sv, dv, 128, 256);
        agg4_kernel<<<N, 128, 0, stream>>>(hb, sv, dv, offsets, srcs, b0, zb, N);
        bn_stats_kernel<256><<<NB_RED, 256, 0, stream>>>(zb, ps, pq, N);
        bn_final_kernel<<<1, 256, 0, stream>>>(ps, pq, g0, be0, scale, shift, N, 256);
        bn_apply_kernel<<<(N * 128 + 255) / 256, 256, 0, stream>>>((uint*)zb, scale, shift,
                                                                   N * 128, 255);
    }
    // ---- layer 1 ----
    {
        mfma_gemm_bt<128, 4><<<NBROW * 2, 256, 0, stream>>>(zb, w1t, hb, as1, ad1, sv, dv, 256, 256);
        agg4_kernel<<<N, 128, 0, stream>>>(hb, sv, dv, offsets, srcs, b1, zb, N);
        bn_stats_kernel<256><<<NB_RED, 256, 0, stream>>>(zb, ps, pq, N);
        bn_final_kernel<<<1, 256, 0, stream>>>(ps, pq, g1, be1, scale, shift, N, 256);
        bn_apply_kernel<<<(N * 128 + 255) / 256, 256, 0, stream>>>((uint*)zb, scale, shift,
                                                                   N * 128, 255);
    }
    // ---- layer 2 (1 head, F=64); BN-apply fused into pool ----
    {
        mfma_gemm_bt<64, 1><<<NBROW, 256, 0, stream>>>(zb, w2t, hb, as2, ad2, sv, dv, 256, 64);
        agg1_kernel<<<N, 64, 0, stream>>>(hb, sv, dv, offsets, srcs, b2, zb, N);
        bn_stats_kernel<64><<<NB_RED, 256, 0, stream>>>(zb, ps, pq, N);
        bn_final_kernel<<<1, 64, 0, stream>>>(ps, pq, g2, be2, scale, shift, N, 64);
    }

    // ---- pooling (BN+ReLU fused) + classifier ----
    pool_kernel<<<NB_RED, 256, 0, stream>>>(zb, scale, shift, psum, pmax, N);
    classify_kernel<<<1, 128, 0, stream>>>(psum, pmax, Wc1, bc1, Wc2, bc2, out, N);
}